// Round 8
// baseline (67.893 us; speedup 1.0000x reference)
//
#include <hip/hip_runtime.h>
#include <hip/hip_bf16.h>

#define B_ 8
#define N_ 16384
#define S_ 1024
#define K_ 32
#define CSTEM 64
#define CPATCH 128
#define INDIM 91
#define LDH 136     // Hs row stride (bf16): 272B, rows 16B-aligned
#define NQ 4        // queries (patches) per block
#define CHUNK 2048  // ball chunk: 256 threads x 8 pts

typedef __attribute__((ext_vector_type(8))) short short8v;  // 8 bf16 = 4 VGPRs
typedef __attribute__((ext_vector_type(4))) float f32x4;

static __device__ __forceinline__ unsigned short f2bf(float f) {
  union { float f; unsigned int u; } v; v.f = f;
  return (unsigned short)((v.u + 0x7FFFu + ((v.u >> 16) & 1u)) >> 16);  // RNE
}

static __device__ __forceinline__ short8v cvt8(const float4 a, const float4 b) {
  unsigned short v[8];
  v[0] = f2bf(a.x); v[1] = f2bf(a.y); v[2] = f2bf(a.z); v[3] = f2bf(a.w);
  v[4] = f2bf(b.x); v[5] = f2bf(b.y); v[6] = f2bf(b.z); v[7] = f2bf(b.w);
  return *(const short8v*)v;
}

// PE/rel fragment: 8 bf16 values for columns [64+kq, 64+kq+8) of one row.
// Same expression as the verified LDS-staged version => identical numerics.
static __device__ __forceinline__ short8v pe_frag(
    float r0, float r1, float r2, int kq)
{
  unsigned short v[8];
  #pragma unroll
  for (int j = 0; j < 8; ++j) {
    const int c = 64 + kq + j;
    float val;
    if (c < 67) {
      val = (c == 64) ? r0 : ((c == 65) ? r1 : r2);
    } else if (c < 91) {
      const int qq = c - 67, d = qq >> 3, rbit = qq & 7, band = rbit & 3;
      const float rel = (d == 0) ? r0 : ((d == 1) ? r1 : r2);
      const float ang = rel * ((float)(1 << band) * 3.14159265358979323846f);
      val = (rbit < 4) ? __sinf(ang) : __cosf(ang);
    } else {
      val = 0.f;
    }
    v[j] = f2bf(val);
  }
  return *(const short8v*)v;
}

// -------- Kernel 0: pack w1/w2 into MFMA B-fragment order (bf16) --------
__global__ __launch_bounds__(256) void pack_weights(
    const float* __restrict__ w1, const float* __restrict__ w2,
    unsigned short* __restrict__ w1p, unsigned short* __restrict__ w2p)
{
  const int id = blockIdx.x * 256 + threadIdx.x;
  if (id < 3 * 8 * 64) {                       // w1: K padded 91->96 (3 ksteps)
    const int l = id & 63, ct = (id >> 6) & 7, ks = id >> 9;
    const int col = 16 * ct + (l & 15);
    const int kb = 32 * ks + (l >> 4) * 8;
    unsigned short v[8];
    #pragma unroll
    for (int j = 0; j < 8; ++j) {
      const int k = kb + j;
      v[j] = (k < INDIM) ? f2bf(w1[k * CPATCH + col]) : (unsigned short)0;
    }
    *(short8v*)&w1p[(size_t)id * 8] = *(const short8v*)v;
  } else if (id < 3 * 8 * 64 + 4 * 8 * 64) {   // w2: 4 ksteps
    const int id2 = id - 3 * 8 * 64;
    const int l = id2 & 63, ct = (id2 >> 6) & 7, ks = id2 >> 9;
    const int col = 16 * ct + (l & 15);
    const int kb = 32 * ks + (l >> 4) * 8;
    unsigned short v[8];
    #pragma unroll
    for (int j = 0; j < 8; ++j) v[j] = f2bf(w2[(kb + j) * CPATCH + col]);
    *(short8v*)&w2p[(size_t)id2 * 8] = *(const short8v*)v;
  }
}

// -------- Fused: joint-4 ball query + reg-direct A-fragments + MFMA MLP ----
// One block = 4 consecutive patches. A-fragments for the MLP are built
// directly in registers (features: 2x float4 from global pf; rel/PE: per-lane
// compute from LDS-stashed coords) - no A staging tile, so LDS ~20KB and
// up to 8 blocks/CU. Hs is double-buffered: 1 barrier per patch.
__global__ __launch_bounds__(256) void fused_patch(
    const float* __restrict__ xyz, const float* __restrict__ pf,
    const float* __restrict__ pc,
    const unsigned short* __restrict__ w1p, const float* __restrict__ b1,
    const unsigned short* __restrict__ w2p, const float* __restrict__ b2,
    float* __restrict__ idx_out, float* __restrict__ out)
{
  const int tid  = threadIdx.x;
  const int lane = tid & 63;
  const int w    = tid >> 6;
  const int bs0  = blockIdx.x * NQ;            // 4 consecutive patches
  const int b    = bs0 >> 10;                  // S_ = 1024, NQ | S_

  __shared__ float scen[3 * NQ];
  __shared__ int   sidx[NQ][K_];
  __shared__ float sxyz[NQ][K_][3];
  __shared__ int   swsum[4][NQ];
  __shared__ int   sfound[NQ];
  __shared__ __align__(16) unsigned short Hs[2][K_][LDH];

  const float* __restrict__ xb  = xyz + (size_t)b * N_ * 3;
  const float* __restrict__ pfb = pf  + (size_t)b * N_ * CSTEM;

  if (tid < 3 * NQ) scen[tid] = pc[bs0 * 3 + tid];
  __syncthreads();

  float cxf[NQ], cyf[NQ], czf[NQ];
  #pragma unroll
  for (int q = 0; q < NQ; ++q) {               // fully unrolled: static indexing
    cxf[q] = scen[q * 3 + 0];
    cyf[q] = scen[q * 3 + 1];
    czf[q] = scen[q * 3 + 2];
  }
  const double rr = 0.2 * 0.2;

  // ---- Ball query: 2048 pts/chunk, 4 queries share every loaded point ----
  int found[NQ] = {0, 0, 0, 0};

  for (int chunk = 0; chunk < N_; chunk += CHUNK) {
    const int i0 = chunk + tid * 8;
    float px[8], py[8], pz[8];
    {
      const float4 v0 = *(const float4*)&xb[i0 * 3 + 0];
      const float4 v1 = *(const float4*)&xb[i0 * 3 + 4];
      const float4 v2 = *(const float4*)&xb[i0 * 3 + 8];
      const float4 v3 = *(const float4*)&xb[i0 * 3 + 12];
      const float4 v4 = *(const float4*)&xb[i0 * 3 + 16];
      const float4 v5 = *(const float4*)&xb[i0 * 3 + 20];
      px[0] = v0.x; py[0] = v0.y; pz[0] = v0.z;
      px[1] = v0.w; py[1] = v1.x; pz[1] = v1.y;
      px[2] = v1.z; py[2] = v1.w; pz[2] = v2.x;
      px[3] = v2.y; py[3] = v2.z; pz[3] = v2.w;
      px[4] = v3.x; py[4] = v3.y; pz[4] = v3.z;
      px[5] = v3.w; py[5] = v4.x; pz[5] = v4.y;
      px[6] = v4.z; py[6] = v4.w; pz[6] = v5.x;
      px[7] = v5.y; py[7] = v5.z; pz[7] = v5.w;
    }

    unsigned mask[NQ];
    #pragma unroll
    for (int q = 0; q < NQ; ++q) {
      mask[q] = 0u;
      if (found[q] < K_) {
        #pragma unroll
        for (int p = 0; p < 8; ++p) {
          const float dxf = px[p] - cxf[q];
          const float dyf = py[p] - cyf[q];
          const float dzf = pz[p] - czf[q];
          const float d2f = fmaf(dxf, dxf, fmaf(dyf, dyf, dzf * dzf));
          bool in;
          if (fabsf(d2f - 0.04f) <= 1e-5f) {      // rare: exact f64 recheck
            const double dx = (double)px[p] - (double)cxf[q];
            const double dy = (double)py[p] - (double)cyf[q];
            const double dz = (double)pz[p] - (double)czf[q];
            in = (dx * dx + dy * dy + dz * dz) <= rr;
          } else {
            in = (d2f < 0.04f);
          }
          if (in) mask[q] |= (1u << p);
        }
      }
    }

    // packed dual prefix scans (counts <=8, inclusive sums <=512 => 16b fields)
    const int c0 = __popc(mask[0]), c1 = __popc(mask[1]);
    const int c2 = __popc(mask[2]), c3 = __popc(mask[3]);
    unsigned pA = (unsigned)c0 | ((unsigned)c1 << 16);
    unsigned pB = (unsigned)c2 | ((unsigned)c3 << 16);
    #pragma unroll
    for (int d = 1; d < 64; d <<= 1) {
      const unsigned vA = (unsigned)__shfl_up((int)pA, d);
      const unsigned vB = (unsigned)__shfl_up((int)pB, d);
      if (lane >= d) { pA += vA; pB += vB; }
    }
    int incl[NQ];
    incl[0] = pA & 0xFFFF; incl[1] = pA >> 16;
    incl[2] = pB & 0xFFFF; incl[3] = pB >> 16;
    if (lane == 63) {
      #pragma unroll
      for (int q = 0; q < NQ; ++q) swsum[w][q] = incl[q];
    }
    __syncthreads();

    int cnt[NQ] = {c0, c1, c2, c3};
    #pragma unroll
    for (int q = 0; q < NQ; ++q) {
      if (found[q] < K_) {
        int pos = found[q] + (incl[q] - cnt[q]);
        #pragma unroll
        for (int v = 0; v < 4; ++v) if (v < w) pos += swsum[v][q];
        #pragma unroll
        for (int p = 0; p < 8; ++p) {
          if (mask[q] & (1u << p)) {
            if (pos < K_) {
              sidx[q][pos] = i0 + p;
              sxyz[q][pos][0] = px[p];
              sxyz[q][pos][1] = py[p];
              sxyz[q][pos][2] = pz[p];
            }
            ++pos;
          }
        }
        found[q] += swsum[0][q] + swsum[1][q] + swsum[2][q] + swsum[3][q];
      }
    }
    __syncthreads();                             // swsum/sidx reuse
    if (found[0] >= K_ && found[1] >= K_ && found[2] >= K_ && found[3] >= K_)
      break;                                     // block-uniform
  }

  // ---- Fill (reference: pad with first found; none found -> index N-1) ----
  if (tid == 0) {
    #pragma unroll
    for (int q = 0; q < NQ; ++q) {
      sfound[q] = found[q];
      if (found[q] == 0) {
        sidx[q][0] = N_ - 1;
        sxyz[q][0][0] = xb[(N_ - 1) * 3 + 0];
        sxyz[q][0][1] = xb[(N_ - 1) * 3 + 1];
        sxyz[q][0][2] = xb[(N_ - 1) * 3 + 2];
      }
    }
  }
  __syncthreads();
  if (tid < NQ * K_) {
    const int q = tid >> 5, j = tid & 31;
    const int fq = sfound[q];
    const int v   = (j < fq && fq > 0) ? sidx[q][j]    : sidx[q][0];
    const float x = (j < fq && fq > 0) ? sxyz[q][j][0] : sxyz[q][0][0];
    const float y = (j < fq && fq > 0) ? sxyz[q][j][1] : sxyz[q][0][1];
    const float z = (j < fq && fq > 0) ? sxyz[q][j][2] : sxyz[q][0][2];
    sidx[q][j] = v;
    sxyz[q][j][0] = x; sxyz[q][j][1] = y; sxyz[q][j][2] = z;
    idx_out[(size_t)bs0 * K_ + tid] = (float)v;
  }
  __syncthreads();

  // ---- Weight fragments + biases (loaded once, used for NQ patches) ----
  short8v w1f[3][2], w2f[4][2];
  #pragma unroll
  for (int ks = 0; ks < 3; ++ks)
    #pragma unroll
    for (int t = 0; t < 2; ++t)
      w1f[ks][t] = *(const short8v*)&w1p[((size_t)(ks * 8 + 2 * w + t) * 64 + lane) * 8];
  #pragma unroll
  for (int ks = 0; ks < 4; ++ks)
    #pragma unroll
    for (int t = 0; t < 2; ++t)
      w2f[ks][t] = *(const short8v*)&w2p[((size_t)(ks * 8 + 2 * w + t) * 64 + lane) * 8];
  const float bias1[2] = { b1[32 * w + (lane & 15)], b1[32 * w + 16 + (lane & 15)] };
  const float bias2[2] = { b2[32 * w + (lane & 15)], b2[32 * w + 16 + (lane & 15)] };

  const int rfr = lane & 15;          // A-fragment rows rfr and 16+rfr
  const int kq  = (lane >> 4) * 8;    // fragment k-offset within a 32-kstep

  // ---- Per patch: reg-direct A-frags -> L1 MFMA -> Hs -> L2 MFMA -> max ----
  #pragma unroll 1
  for (int q = 0; q < NQ; ++q) {
    const int hb = q & 1;             // Hs ping-pong buffer
    // centers from LDS (runtime q => no register-array dynamic indexing)
    const float cq0 = scen[q * 3 + 0];
    const float cq1 = scen[q * 3 + 1];
    const float cq2 = scen[q * 3 + 2];

    const int r0 = sidx[q][rfr];
    const int r1 = sidx[q][16 + rfr];

    // feature fragments: ks=0 cols kq..kq+7, ks=1 cols 32+kq..+7 (global pf)
    const float4 u00 = *(const float4*)&pfb[(size_t)r0 * CSTEM + kq];
    const float4 u01 = *(const float4*)&pfb[(size_t)r0 * CSTEM + kq + 4];
    const float4 u02 = *(const float4*)&pfb[(size_t)r0 * CSTEM + 32 + kq];
    const float4 u03 = *(const float4*)&pfb[(size_t)r0 * CSTEM + 32 + kq + 4];
    const float4 u10 = *(const float4*)&pfb[(size_t)r1 * CSTEM + kq];
    const float4 u11 = *(const float4*)&pfb[(size_t)r1 * CSTEM + kq + 4];
    const float4 u12 = *(const float4*)&pfb[(size_t)r1 * CSTEM + 32 + kq];
    const float4 u13 = *(const float4*)&pfb[(size_t)r1 * CSTEM + 32 + kq + 4];

    // rel/PE fragments (ks=2, cols 64+kq..+7), same math as verified version
    const short8v a0k2 = pe_frag(sxyz[q][rfr][0] - cq0,
                                 sxyz[q][rfr][1] - cq1,
                                 sxyz[q][rfr][2] - cq2, kq);
    const short8v a1k2 = pe_frag(sxyz[q][16 + rfr][0] - cq0,
                                 sxyz[q][16 + rfr][1] - cq1,
                                 sxyz[q][16 + rfr][2] - cq2, kq);

    const short8v a0k0 = cvt8(u00, u01), a0k1 = cvt8(u02, u03);
    const short8v a1k0 = cvt8(u10, u11), a1k1 = cvt8(u12, u13);

    f32x4 acc[2][2] = {};
    acc[0][0] = __builtin_amdgcn_mfma_f32_16x16x32_bf16(a0k0, w1f[0][0], acc[0][0], 0, 0, 0);
    acc[0][1] = __builtin_amdgcn_mfma_f32_16x16x32_bf16(a0k0, w1f[0][1], acc[0][1], 0, 0, 0);
    acc[1][0] = __builtin_amdgcn_mfma_f32_16x16x32_bf16(a1k0, w1f[0][0], acc[1][0], 0, 0, 0);
    acc[1][1] = __builtin_amdgcn_mfma_f32_16x16x32_bf16(a1k0, w1f[0][1], acc[1][1], 0, 0, 0);
    acc[0][0] = __builtin_amdgcn_mfma_f32_16x16x32_bf16(a0k1, w1f[1][0], acc[0][0], 0, 0, 0);
    acc[0][1] = __builtin_amdgcn_mfma_f32_16x16x32_bf16(a0k1, w1f[1][1], acc[0][1], 0, 0, 0);
    acc[1][0] = __builtin_amdgcn_mfma_f32_16x16x32_bf16(a1k1, w1f[1][0], acc[1][0], 0, 0, 0);
    acc[1][1] = __builtin_amdgcn_mfma_f32_16x16x32_bf16(a1k1, w1f[1][1], acc[1][1], 0, 0, 0);
    acc[0][0] = __builtin_amdgcn_mfma_f32_16x16x32_bf16(a0k2, w1f[2][0], acc[0][0], 0, 0, 0);
    acc[0][1] = __builtin_amdgcn_mfma_f32_16x16x32_bf16(a0k2, w1f[2][1], acc[0][1], 0, 0, 0);
    acc[1][0] = __builtin_amdgcn_mfma_f32_16x16x32_bf16(a1k2, w1f[2][0], acc[1][0], 0, 0, 0);
    acc[1][1] = __builtin_amdgcn_mfma_f32_16x16x32_bf16(a1k2, w1f[2][1], acc[1][1], 0, 0, 0);

    #pragma unroll
    for (int rt = 0; rt < 2; ++rt)
      #pragma unroll
      for (int t = 0; t < 2; ++t)
        #pragma unroll
        for (int reg = 0; reg < 4; ++reg) {
          const float h = fmaxf(acc[rt][t][reg] + bias1[t], 0.f);
          const int row = 16 * rt + (lane >> 4) * 4 + reg;
          const int col = 32 * w + 16 * t + (lane & 15);
          Hs[hb][row][col] = f2bf(h);
        }
    __syncthreads();   // Hs[hb] complete (also: prev patch's reads all done)

    f32x4 acc2[2][2] = {};
    #pragma unroll
    for (int ks = 0; ks < 4; ++ks) {
      const int k0 = ks * 32 + kq;
      const short8v a0 = *(const short8v*)&Hs[hb][rfr][k0];
      const short8v a1 = *(const short8v*)&Hs[hb][16 + rfr][k0];
      acc2[0][0] = __builtin_amdgcn_mfma_f32_16x16x32_bf16(a0, w2f[ks][0], acc2[0][0], 0, 0, 0);
      acc2[0][1] = __builtin_amdgcn_mfma_f32_16x16x32_bf16(a0, w2f[ks][1], acc2[0][1], 0, 0, 0);
      acc2[1][0] = __builtin_amdgcn_mfma_f32_16x16x32_bf16(a1, w2f[ks][0], acc2[1][0], 0, 0, 0);
      acc2[1][1] = __builtin_amdgcn_mfma_f32_16x16x32_bf16(a1, w2f[ks][1], acc2[1][1], 0, 0, 0);
    }
    float m0 = -3.4e38f, m1 = -3.4e38f;
    #pragma unroll
    for (int rt = 0; rt < 2; ++rt)
      #pragma unroll
      for (int reg = 0; reg < 4; ++reg) {
        m0 = fmaxf(m0, acc2[rt][0][reg]);
        m1 = fmaxf(m1, acc2[rt][1][reg]);
      }
    m0 += bias2[0];
    m1 += bias2[1];
    m0 = fmaxf(m0, __shfl_xor(m0, 16));
    m0 = fmaxf(m0, __shfl_xor(m0, 32));
    m1 = fmaxf(m1, __shfl_xor(m1, 16));
    m1 = fmaxf(m1, __shfl_xor(m1, 32));
    if (lane < 16) {
      out[(size_t)(bs0 + q) * CPATCH + 32 * w + lane]      = m0;
      out[(size_t)(bs0 + q) * CPATCH + 32 * w + 16 + lane] = m1;
    }
    // no trailing barrier: next patch writes the OTHER Hs buffer; its barrier
    // transitively guarantees this patch's reads completed before buffer reuse
  }
}

extern "C" void kernel_launch(void* const* d_in, const int* in_sizes, int n_in,
                              void* d_out, int out_size, void* d_ws, size_t ws_size,
                              hipStream_t stream) {
  const float* xyz = (const float*)d_in[0];
  const float* pf  = (const float*)d_in[1];
  const float* pc  = (const float*)d_in[2];
  const float* w1  = (const float*)d_in[3];
  const float* b1  = (const float*)d_in[4];
  const float* w2  = (const float*)d_in[5];
  const float* b2  = (const float*)d_in[6];

  float* out     = (float*)d_out;
  float* idx_out = out + (size_t)B_ * S_ * CPATCH;

  unsigned short* w1p = (unsigned short*)d_ws;
  unsigned short* w2p = w1p + 96 * 128;

  pack_weights<<<14, 256, 0, stream>>>(w1, w2, w1p, w2p);
  fused_patch<<<B_ * S_ / NQ, 256, 0, stream>>>(xyz, pf, pc, w1p, b1, w2p, b2,
                                                idx_out, out);
}

// Round 9
// 50.221 us; speedup vs baseline: 1.3519x; 1.3519x over previous
//
#include <hip/hip_runtime.h>
#include <hip/hip_bf16.h>

#define B_ 8
#define N_ 16384
#define S_ 1024
#define K_ 32
#define CSTEM 64
#define CPATCH 128
#define INDIM 91
#define LDA 104     // As row stride (bf16)
#define LDH 136     // Hs row stride (bf16)
#define NQ 4        // queries per block = waves per block

typedef __attribute__((ext_vector_type(8))) short short8v;  // 8 bf16 = 4 VGPRs
typedef __attribute__((ext_vector_type(4))) float f32x4;

static __device__ __forceinline__ unsigned short f2bf(float f) {
  union { float f; unsigned int u; } v; v.f = f;
  return (unsigned short)((v.u + 0x7FFFu + ((v.u >> 16) & 1u)) >> 16);  // RNE
}

// -------- Kernel 0: pack w1/w2 into MFMA B-fragment order (bf16) --------
__global__ __launch_bounds__(256) void pack_weights(
    const float* __restrict__ w1, const float* __restrict__ w2,
    unsigned short* __restrict__ w1p, unsigned short* __restrict__ w2p)
{
  const int id = blockIdx.x * 256 + threadIdx.x;
  if (id < 3 * 8 * 64) {                       // w1: K padded 91->96 (3 ksteps)
    const int l = id & 63, ct = (id >> 6) & 7, ks = id >> 9;
    const int col = 16 * ct + (l & 15);
    const int kb = 32 * ks + (l >> 4) * 8;
    unsigned short v[8];
    #pragma unroll
    for (int j = 0; j < 8; ++j) {
      const int k = kb + j;
      v[j] = (k < INDIM) ? f2bf(w1[k * CPATCH + col]) : (unsigned short)0;
    }
    *(short8v*)&w1p[(size_t)id * 8] = *(const short8v*)v;
  } else if (id < 3 * 8 * 64 + 4 * 8 * 64) {   // w2: 4 ksteps
    const int id2 = id - 3 * 8 * 64;
    const int l = id2 & 63, ct = (id2 >> 6) & 7, ks = id2 >> 9;
    const int col = 16 * ct + (l & 15);
    const int kb = 32 * ks + (l >> 4) * 8;
    unsigned short v[8];
    #pragma unroll
    for (int j = 0; j < 8; ++j) v[j] = f2bf(w2[(kb + j) * CPATCH + col]);
    *(short8v*)&w2p[(size_t)id2 * 8] = *(const short8v*)v;
  }
}

// component accessor for an unrolled float4 array (IDX must be compile-time)
#define FCOMP(V, IDX) (((IDX) & 3) == 0 ? (V)[(IDX) >> 2].x : \
                       ((IDX) & 3) == 1 ? (V)[(IDX) >> 2].y : \
                       ((IDX) & 3) == 2 ? (V)[(IDX) >> 2].z : (V)[(IDX) >> 2].w)

// -------- Fused: per-wave barrier-free ball query + R7 MLP ----------------
// One block = 4 patches; wave w owns query w end-to-end during the ball
// phase (1024 pts/iter, wave-local prefix, independent early exit, NO block
// barriers). Distance decisions bit-identical to the verified f32-band+f64
// expression. MLP phase identical to the verified R7 version.
__global__ __launch_bounds__(256) void fused_patch(
    const float* __restrict__ xyz, const float* __restrict__ pf,
    const float* __restrict__ pc,
    const unsigned short* __restrict__ w1p, const float* __restrict__ b1,
    const unsigned short* __restrict__ w2p, const float* __restrict__ b2,
    float* __restrict__ idx_out, float* __restrict__ out)
{
  const int tid  = threadIdx.x;
  const int lane = tid & 63;
  const int w    = tid >> 6;
  const int bs0  = blockIdx.x * NQ;
  const int b    = bs0 >> 10;                  // S_ = 1024, NQ | S_

  __shared__ float scen[3 * NQ];
  __shared__ int   sidx[NQ][K_];
  __shared__ float sxyz[NQ][K_][3];
  __shared__ int   sfound[NQ];
  __shared__ __align__(16) unsigned short As[NQ * K_][LDA];
  __shared__ __align__(16) unsigned short Hs[K_][LDH];

  const float* __restrict__ xb  = xyz + (size_t)b * N_ * 3;
  const float* __restrict__ pfb = pf  + (size_t)b * N_ * CSTEM;

  if (tid < 3 * NQ) scen[tid] = pc[bs0 * 3 + tid];
  __syncthreads();

  // ---- Ball phase: wave w scans for query w, no block barriers ----
  {
    const int q = w;
    const float cx = scen[q * 3 + 0];
    const float cy = scen[q * 3 + 1];
    const float cz = scen[q * 3 + 2];
    const double rr = 0.2 * 0.2;

    int found = 0;
    for (int base = 0; base < N_; base += 1024) {
      const int i0 = base + lane * 16;         // 16 consecutive pts per lane
      float4 v[12];
      #pragma unroll
      for (int t = 0; t < 12; ++t)
        v[t] = *(const float4*)&xb[i0 * 3 + t * 4];

      unsigned mask = 0u;
      #pragma unroll
      for (int p = 0; p < 16; ++p) {
        const float X = FCOMP(v, 3 * p + 0);
        const float Y = FCOMP(v, 3 * p + 1);
        const float Z = FCOMP(v, 3 * p + 2);
        const float dxf = X - cx, dyf = Y - cy, dzf = Z - cz;
        const float d2f = fmaf(dxf, dxf, fmaf(dyf, dyf, dzf * dzf));
        bool in;
        if (fabsf(d2f - 0.04f) <= 1e-5f) {     // rare exact f64 recheck
          const double dx = (double)X - (double)cx;
          const double dy = (double)Y - (double)cy;
          const double dz = (double)Z - (double)cz;
          in = (dx * dx + dy * dy + dz * dz) <= rr;
        } else {
          in = (d2f < 0.04f);
        }
        if (in) mask |= (1u << p);
      }

      const int cnt = __popc(mask);
      int incl = cnt;                          // wave-inclusive prefix
      #pragma unroll
      for (int d = 1; d < 64; d <<= 1) {
        const int t = __shfl_up(incl, d);
        if (lane >= d) incl += t;
      }
      const int tot = __shfl(incl, 63);

      int pos = found + (incl - cnt);
      #pragma unroll
      for (int p = 0; p < 16; ++p) {           // static p: no dyn reg indexing
        if (mask & (1u << p)) {
          if (pos < K_) {
            sidx[q][pos] = i0 + p;
            sxyz[q][pos][0] = FCOMP(v, 3 * p + 0);
            sxyz[q][pos][1] = FCOMP(v, 3 * p + 1);
            sxyz[q][pos][2] = FCOMP(v, 3 * p + 2);
          }
          ++pos;
        }
      }
      found += tot;
      if (found >= K_) break;                  // wave-uniform
    }
    if (lane == 0) sfound[q] = found;
  }
  __syncthreads();

  // ---- Fill (pad with first found; none found -> index N-1) ----
  if (tid < NQ && sfound[tid] == 0) {
    sidx[tid][0] = N_ - 1;
    sxyz[tid][0][0] = xb[(N_ - 1) * 3 + 0];
    sxyz[tid][0][1] = xb[(N_ - 1) * 3 + 1];
    sxyz[tid][0][2] = xb[(N_ - 1) * 3 + 2];
  }
  __syncthreads();
  if (tid < NQ * K_) {
    const int q = tid >> 5, j = tid & 31;
    const int fq = sfound[q];
    const int v   = (j < fq && fq > 0) ? sidx[q][j]    : sidx[q][0];
    const float x = (j < fq && fq > 0) ? sxyz[q][j][0] : sxyz[q][0][0];
    const float y = (j < fq && fq > 0) ? sxyz[q][j][1] : sxyz[q][0][1];
    const float z = (j < fq && fq > 0) ? sxyz[q][j][2] : sxyz[q][0][2];
    sidx[q][j] = v;
    sxyz[q][j][0] = x; sxyz[q][j][1] = y; sxyz[q][j][2] = z;
    idx_out[(size_t)bs0 * K_ + tid] = (float)v;
  }
  __syncthreads();

  // ---- Weight fragments + biases (loaded once, used for NQ patches) ----
  short8v w1f[3][2], w2f[4][2];
  #pragma unroll
  for (int ks = 0; ks < 3; ++ks)
    #pragma unroll
    for (int t = 0; t < 2; ++t)
      w1f[ks][t] = *(const short8v*)&w1p[((size_t)(ks * 8 + 2 * w + t) * 64 + lane) * 8];
  #pragma unroll
  for (int ks = 0; ks < 4; ++ks)
    #pragma unroll
    for (int t = 0; t < 2; ++t)
      w2f[ks][t] = *(const short8v*)&w2p[((size_t)(ks * 8 + 2 * w + t) * 64 + lane) * 8];
  const float bias1[2] = { b1[32 * w + (lane & 15)], b1[32 * w + 16 + (lane & 15)] };
  const float bias2[2] = { b2[32 * w + (lane & 15)], b2[32 * w + 16 + (lane & 15)] };

  // ---- Batched gather: all 4 patches staged before any MFMA (R7) ----
  {
    const int row = tid >> 3, sub = tid & 7;   // feature loads, 8 thr/row
    #pragma unroll
    for (int q = 0; q < NQ; ++q) {
      const int r = sidx[q][row];
      const float4 f0 = *(const float4*)&pfb[(size_t)r * CSTEM + sub * 8];
      const float4 f1 = *(const float4*)&pfb[(size_t)r * CSTEM + sub * 8 + 4];
      unsigned short vv[8];
      vv[0] = f2bf(f0.x); vv[1] = f2bf(f0.y); vv[2] = f2bf(f0.z); vv[3] = f2bf(f0.w);
      vv[4] = f2bf(f1.x); vv[5] = f2bf(f1.y); vv[6] = f2bf(f1.z); vv[7] = f2bf(f1.w);
      *(short8v*)&As[q * K_ + row][sub * 8] = *(const short8v*)vv;
    }
  }
  {
    const int row = tid & 31, j = tid >> 5;    // rel+PE, 8 thr/row x 4 cols
    #pragma unroll
    for (int q = 0; q < NQ; ++q) {
      const float r0 = sxyz[q][row][0] - scen[q * 3 + 0];
      const float r1 = sxyz[q][row][1] - scen[q * 3 + 1];
      const float r2 = sxyz[q][row][2] - scen[q * 3 + 2];
      #pragma unroll
      for (int cc = 0; cc < 4; ++cc) {
        const int c = 64 + 4 * j + cc;
        float val;
        if (c < 67) val = (c == 64) ? r0 : ((c == 65) ? r1 : r2);
        else if (c < 91) {
          const int qq = c - 67, d = qq >> 3, rbit = qq & 7, band = rbit & 3;
          const float rel = (d == 0) ? r0 : ((d == 1) ? r1 : r2);
          const float ang = rel * ((float)(1 << band) * 3.14159265358979323846f);
          val = (rbit < 4) ? __sinf(ang) : __cosf(ang);
        } else val = 0.f;
        As[q * K_ + row][c] = f2bf(val);
      }
    }
  }
  __syncthreads();

  // ---- Per patch: L1 MFMA -> relu -> Hs -> L2 MFMA -> column max (R7) ----
  #pragma unroll 1
  for (int q = 0; q < NQ; ++q) {
    f32x4 acc[2][2] = {};
    #pragma unroll
    for (int ks = 0; ks < 3; ++ks) {
      const int k0 = ks * 32 + (lane >> 4) * 8;
      const short8v a0 = *(const short8v*)&As[q * K_ + (lane & 15)][k0];
      const short8v a1 = *(const short8v*)&As[q * K_ + 16 + (lane & 15)][k0];
      acc[0][0] = __builtin_amdgcn_mfma_f32_16x16x32_bf16(a0, w1f[ks][0], acc[0][0], 0, 0, 0);
      acc[0][1] = __builtin_amdgcn_mfma_f32_16x16x32_bf16(a0, w1f[ks][1], acc[0][1], 0, 0, 0);
      acc[1][0] = __builtin_amdgcn_mfma_f32_16x16x32_bf16(a1, w1f[ks][0], acc[1][0], 0, 0, 0);
      acc[1][1] = __builtin_amdgcn_mfma_f32_16x16x32_bf16(a1, w1f[ks][1], acc[1][1], 0, 0, 0);
    }
    #pragma unroll
    for (int rt = 0; rt < 2; ++rt)
      #pragma unroll
      for (int t = 0; t < 2; ++t)
        #pragma unroll
        for (int reg = 0; reg < 4; ++reg) {
          const float h = fmaxf(acc[rt][t][reg] + bias1[t], 0.f);
          const int row = 16 * rt + (lane >> 4) * 4 + reg;
          const int col = 32 * w + 16 * t + (lane & 15);
          Hs[row][col] = f2bf(h);
        }
    __syncthreads();

    f32x4 acc2[2][2] = {};
    #pragma unroll
    for (int ks = 0; ks < 4; ++ks) {
      const int k0 = ks * 32 + (lane >> 4) * 8;
      const short8v a0 = *(const short8v*)&Hs[(lane & 15)][k0];
      const short8v a1 = *(const short8v*)&Hs[16 + (lane & 15)][k0];
      acc2[0][0] = __builtin_amdgcn_mfma_f32_16x16x32_bf16(a0, w2f[ks][0], acc2[0][0], 0, 0, 0);
      acc2[0][1] = __builtin_amdgcn_mfma_f32_16x16x32_bf16(a0, w2f[ks][1], acc2[0][1], 0, 0, 0);
      acc2[1][0] = __builtin_amdgcn_mfma_f32_16x16x32_bf16(a1, w2f[ks][0], acc2[1][0], 0, 0, 0);
      acc2[1][1] = __builtin_amdgcn_mfma_f32_16x16x32_bf16(a1, w2f[ks][1], acc2[1][1], 0, 0, 0);
    }
    float m0 = -3.4e38f, m1 = -3.4e38f;
    #pragma unroll
    for (int rt = 0; rt < 2; ++rt)
      #pragma unroll
      for (int reg = 0; reg < 4; ++reg) {
        m0 = fmaxf(m0, acc2[rt][0][reg]);
        m1 = fmaxf(m1, acc2[rt][1][reg]);
      }
    m0 += bias2[0];
    m1 += bias2[1];
    m0 = fmaxf(m0, __shfl_xor(m0, 16));
    m0 = fmaxf(m0, __shfl_xor(m0, 32));
    m1 = fmaxf(m1, __shfl_xor(m1, 16));
    m1 = fmaxf(m1, __shfl_xor(m1, 32));
    if (lane < 16) {
      out[(size_t)(bs0 + q) * CPATCH + 32 * w + lane]      = m0;
      out[(size_t)(bs0 + q) * CPATCH + 32 * w + 16 + lane] = m1;
    }
    __syncthreads();                           // Hs reuse next patch
  }
}

extern "C" void kernel_launch(void* const* d_in, const int* in_sizes, int n_in,
                              void* d_out, int out_size, void* d_ws, size_t ws_size,
                              hipStream_t stream) {
  const float* xyz = (const float*)d_in[0];
  const float* pf  = (const float*)d_in[1];
  const float* pc  = (const float*)d_in[2];
  const float* w1  = (const float*)d_in[3];
  const float* b1  = (const float*)d_in[4];
  const float* w2  = (const float*)d_in[5];
  const float* b2  = (const float*)d_in[6];

  float* out     = (float*)d_out;
  float* idx_out = out + (size_t)B_ * S_ * CPATCH;

  unsigned short* w1p = (unsigned short*)d_ws;
  unsigned short* w2p = w1p + 96 * 128;

  pack_weights<<<14, 256, 0, stream>>>(w1, w2, w1p, w2p);
  fused_patch<<<B_ * S_ / NQ, 256, 0, stream>>>(xyz, pf, pc, w1p, b1, w2p, b2,
                                                idx_out, out);
}